// Round 1
// baseline (576.371 us; speedup 1.0000x reference)
//
#include <hip/hip_runtime.h>
#include <hip/hip_bf16.h>
#include <math.h>

typedef __bf16 bf16;
typedef bf16 bf16x8 __attribute__((ext_vector_type(8)));
typedef bf16 bf16x4 __attribute__((ext_vector_type(4)));
typedef float f32x4 __attribute__((ext_vector_type(4)));

#define NFRM 16
#define SEQ  1472
#define TOK  (NFRM * SEQ)   /* 23552 */
#define DIM_ 1024
#define NH_  16
#define HD_  64

// ---------------------------------------------------------------------------
// async global->LDS, 16B per lane. LDS dest must be wave-uniform base.
// ---------------------------------------------------------------------------
__device__ __forceinline__ void load_lds_16B(const void* g, void* l) {
  __builtin_amdgcn_global_load_lds(
      (const __attribute__((address_space(1))) unsigned int*)g,
      (__attribute__((address_space(3))) unsigned int*)l,
      16, 0, 0);
}

// ---------------------------------------------------------------------------
// fp32 -> bf16 conversion (8 elems/thread, 16B stores). n % 2048 == 0.
// ---------------------------------------------------------------------------
__global__ __launch_bounds__(256) void cvt_bf16(const float* __restrict__ s,
                                                bf16* __restrict__ d, int n) {
  size_t i = ((size_t)blockIdx.x * 256 + threadIdx.x) * 8;
  if (i >= (size_t)n) return;
  f32x4 a = *(const f32x4*)(s + i);
  f32x4 b = *(const f32x4*)(s + i + 4);
  bf16x8 o;
  o[0] = (bf16)a[0]; o[1] = (bf16)a[1]; o[2] = (bf16)a[2]; o[3] = (bf16)a[3];
  o[4] = (bf16)b[0]; o[5] = (bf16)b[1]; o[6] = (bf16)b[2]; o[7] = (bf16)b[3];
  *(bf16x8*)(d + i) = o;
}

// ---------------------------------------------------------------------------
// m97-structure GEMM: C[M][1024] = A[M][1024] @ B[1024][1024]^T + bias
// (B stored row-major [n][k], i.e. K-major — matches W layout for x @ W.T)
// 128x128 tile, BK=32, 256 threads = 4 waves, each wave 4x4 of 16x16x32 MFMA.
// ---------------------------------------------------------------------------
template <typename OutT>
__device__ __forceinline__ void gemm_body(const bf16* __restrict__ A,
                                          const bf16* __restrict__ B,
                                          const float* __restrict__ bias,
                                          OutT* __restrict__ C,
                                          bf16* As, bf16* Bs) {
  const int tid  = threadIdx.x;
  const int wave = tid >> 6;
  const int lane = tid & 63;
  const size_t am0 = (size_t)blockIdx.x * 128;
  const size_t bn0 = (size_t)blockIdx.y * 128;

  f32x4 acc[4][4];
#pragma unroll
  for (int i = 0; i < 4; ++i)
#pragma unroll
    for (int j = 0; j < 4; ++j) {
      f32x4 z = {0.f, 0.f, 0.f, 0.f};
      acc[i][j] = z;
    }

  const int wm   = (wave >> 1) * 64;   // wave's 64x64 quadrant
  const int wn   = (wave & 1) * 64;
  const int frow = lane & 15;          // fragment row (m or n)
  const int fko  = (lane >> 4) * 8;    // fragment k offset (quad*8)

  for (int k0 = 0; k0 < DIM_; k0 += 32) {
    // stage A-tile (128x32 bf16 = 8KB) and B-tile: 512 16B-chunks each,
    // chunk c -> row c>>2, k-chunk c&3; LDS offset = c*16 bytes (row-major).
#pragma unroll
    for (int it = 0; it < 2; ++it) {
      const int cb  = it * 256 + wave * 64;  // wave-uniform chunk base
      const int c   = cb + lane;
      const int row = c >> 2;
      const int kc  = (c & 3) * 8;
      load_lds_16B(A + (am0 + row) * DIM_ + k0 + kc, As + cb * 8);
      load_lds_16B(B + (bn0 + row) * DIM_ + k0 + kc, Bs + cb * 8);
    }
    __syncthreads();
    bf16x8 af[4], bfv[4];
#pragma unroll
    for (int i = 0; i < 4; ++i)
      af[i] = *(const bf16x8*)(As + (wm + i * 16 + frow) * 32 + fko);
#pragma unroll
    for (int j = 0; j < 4; ++j)
      bfv[j] = *(const bf16x8*)(Bs + (wn + j * 16 + frow) * 32 + fko);
#pragma unroll
    for (int i = 0; i < 4; ++i)
#pragma unroll
      for (int j = 0; j < 4; ++j)
        acc[i][j] = __builtin_amdgcn_mfma_f32_16x16x32_bf16(af[i], bfv[j],
                                                            acc[i][j], 0, 0, 0);
    __syncthreads();
  }

  // epilogue: C/D layout col = lane&15, row = (lane>>4)*4 + r  [m89/m91]
  const int cl = lane & 15;
  const int rq = (lane >> 4) * 4;
#pragma unroll
  for (int i = 0; i < 4; ++i)
#pragma unroll
    for (int j = 0; j < 4; ++j) {
      const int nc   = (int)bn0 + wn + j * 16 + cl;
      const float bb = bias[nc];
#pragma unroll
      for (int r = 0; r < 4; ++r) {
        const size_t mr = am0 + wm + i * 16 + rq + r;
        C[mr * DIM_ + nc] = (OutT)(acc[i][j][r] + bb);
      }
    }
}

__global__ __launch_bounds__(256) void gemm_qkv(
    const bf16* __restrict__ A,
    const bf16* __restrict__ Bq, const bf16* __restrict__ Bk,
    const bf16* __restrict__ Bv,
    const float* __restrict__ bq, const float* __restrict__ bk,
    const float* __restrict__ bv,
    bf16* __restrict__ Cq, bf16* __restrict__ Ck, bf16* __restrict__ Cv) {
  __shared__ __align__(16) bf16 As[128 * 32];
  __shared__ __align__(16) bf16 Bs[128 * 32];
  const int z = blockIdx.z;
  const bf16* B    = (z == 0) ? Bq : (z == 1) ? Bk : Bv;
  const float* bia = (z == 0) ? bq : (z == 1) ? bk : bv;
  bf16* C          = (z == 0) ? Cq : (z == 1) ? Ck : Cv;
  gemm_body<bf16>(A, B, bia, C, As, Bs);
}

__global__ __launch_bounds__(256) void gemm_out(
    const bf16* __restrict__ A, const bf16* __restrict__ B,
    const float* __restrict__ bias, float* __restrict__ C) {
  __shared__ __align__(16) bf16 As[128 * 32];
  __shared__ __align__(16) bf16 Bs[128 * 32];
  gemm_body<float>(A, B, bias, C, As, Bs);
}

// ---------------------------------------------------------------------------
// In-place RMSNorm + RoPE on q and k. One block per (t, frame) token row.
// position p = frame*SEQ + t  (row index itself).
// ---------------------------------------------------------------------------
__global__ __launch_bounds__(256) void norm_rope(
    bf16* __restrict__ q, bf16* __restrict__ k,
    const float* __restrict__ nqw, const float* __restrict__ nkw,
    const float* __restrict__ fcos, const float* __restrict__ fsin) {
  const int t   = blockIdx.x;
  const int fi  = blockIdx.y;
  const int tid = threadIdx.x;
  const int lane = tid & 63, wave = tid >> 6;
  const size_t row  = (size_t)fi * SEQ + t;
  const size_t base = row * DIM_;
  __shared__ float red[4];

  const int e0 = tid * 4;            // 4 consecutive elems = 2 rope pairs
  const int j0 = (e0 & 63) >> 1;     // pair index within head (0..30, even)
  const float c0 = fcos[row * 32 + j0],     s0 = fsin[row * 32 + j0];
  const float c1 = fcos[row * 32 + j0 + 1], s1 = fsin[row * 32 + j0 + 1];

  for (int which = 0; which < 2; ++which) {
    bf16* buf      = which ? k : q;
    const float* w = which ? nkw : nqw;
    bf16x4 xv = *(const bf16x4*)(buf + base + e0);
    float x0 = (float)xv[0], x1 = (float)xv[1];
    float x2 = (float)xv[2], x3 = (float)xv[3];
    float ss = x0 * x0 + x1 * x1 + x2 * x2 + x3 * x3;
#pragma unroll
    for (int off = 32; off > 0; off >>= 1) ss += __shfl_down(ss, off);
    if (lane == 0) red[wave] = ss;
    __syncthreads();
    const float tot = red[0] + red[1] + red[2] + red[3];
    const float rs  = rsqrtf(tot * (1.0f / 1024.0f) + 1e-6f);
    x0 *= rs * w[e0];     x1 *= rs * w[e0 + 1];
    x2 *= rs * w[e0 + 2]; x3 *= rs * w[e0 + 3];
    bf16x4 ov;
    ov[0] = (bf16)(x0 * c0 - x1 * s0);
    ov[1] = (bf16)(x0 * s0 + x1 * c0);
    ov[2] = (bf16)(x2 * c1 - x3 * s1);
    ov[3] = (bf16)(x2 * s1 + x3 * c1);
    *(bf16x4*)(buf + base + e0) = ov;
    __syncthreads();   // protect red[] before next tensor
  }
}

// ---------------------------------------------------------------------------
// Windowed causal attention over the frame axis (len 16, window 8).
// One block per (t, head). q/k/v layout: [frame*SEQ + t][DIM], head chunk 64.
// Output layout o[(frame*SEQ + t)*DIM + h*64 + d]  (the reference transpose).
// ---------------------------------------------------------------------------
__global__ __launch_bounds__(256) void attn_win(
    const bf16* __restrict__ q, const bf16* __restrict__ k,
    const bf16* __restrict__ v, bf16* __restrict__ o) {
  const int t   = blockIdx.x;
  const int h   = blockIdx.y;
  const int tid = threadIdx.x;
  // +1 float row pad -> k/v stride-64 reads hit distinct banks
  __shared__ float qs[16 * 65], ks[16 * 65], vs[16 * 65];
  __shared__ float ps[16 * 16];

  {
    const int r  = tid >> 4;            // frame 0..15
    const int c4 = (tid & 15) * 4;      // dim 0..60
    const size_t g = ((size_t)r * SEQ + t) * DIM_ + h * HD_ + c4;
    bf16x4 qv = *(const bf16x4*)(q + g);
    bf16x4 kv = *(const bf16x4*)(k + g);
    bf16x4 vv = *(const bf16x4*)(v + g);
    const int l = r * 65 + c4;
#pragma unroll
    for (int i = 0; i < 4; ++i) {
      qs[l + i] = (float)qv[i];
      ks[l + i] = (float)kv[i];
      vs[l + i] = (float)vv[i];
    }
  }
  __syncthreads();

  const int fq = tid >> 4, fk = tid & 15;
  float s = 0.f;
#pragma unroll
  for (int d = 0; d < 64; ++d) s += qs[fq * 65 + d] * ks[fk * 65 + d];
  const bool valid = (fk <= fq) && (fq - fk < 8);
  s = valid ? s * 0.125f : -1e30f;

  // softmax across the 16 lanes sharing fq (contiguous within a wave)
  float m = s;
#pragma unroll
  for (int off = 8; off > 0; off >>= 1) m = fmaxf(m, __shfl_xor(m, off, 16));
  const float p = __expf(s - m);
  float sum = p;
#pragma unroll
  for (int off = 8; off > 0; off >>= 1) sum += __shfl_xor(sum, off, 16);
  ps[fq * 16 + fk] = p / sum;
  __syncthreads();

  const int d  = tid & 63;
  const int r0 = tid >> 6;
#pragma unroll
  for (int rep = 0; rep < 4; ++rep) {
    const int row = r0 * 4 + rep;
    float acc = 0.f;
#pragma unroll
    for (int f2 = 0; f2 < 16; ++f2) acc += ps[row * 16 + f2] * vs[f2 * 65 + d];
    o[((size_t)row * SEQ + t) * DIM_ + h * HD_ + d] = (bf16)acc;
  }
}

// ---------------------------------------------------------------------------
extern "C" void kernel_launch(void* const* d_in, const int* in_sizes, int n_in,
                              void* d_out, int out_size, void* d_ws,
                              size_t ws_size, hipStream_t stream) {
  const float* x    = (const float*)d_in[0];
  const float* fcos = (const float*)d_in[1];
  const float* fsin = (const float*)d_in[2];
  const float* q_w  = (const float*)d_in[3];
  const float* q_b  = (const float*)d_in[4];
  const float* k_w  = (const float*)d_in[5];
  const float* k_b  = (const float*)d_in[6];
  const float* v_w  = (const float*)d_in[7];
  const float* v_b  = (const float*)d_in[8];
  const float* o_w  = (const float*)d_in[9];
  const float* o_b  = (const float*)d_in[10];
  const float* nqw  = (const float*)d_in[11];
  const float* nkw  = (const float*)d_in[12];
  float* out = (float*)d_out;

  char* ws = (char*)d_ws;
  const size_t SZ  = (size_t)TOK * DIM_ * 2;   // 48,234,496 B (one bf16 tensor)
  const size_t WSZ = (size_t)DIM_ * DIM_ * 2;  // 2 MiB per weight
  bf16* xb = (bf16*)(ws);
  bf16* wq = (bf16*)(ws + SZ);
  bf16* wk = (bf16*)(ws + SZ + WSZ);
  bf16* wv = (bf16*)(ws + SZ + 2 * WSZ);
  bf16* wo = (bf16*)(ws + SZ + 3 * WSZ);
  bf16* qq = (bf16*)(ws + SZ + 4 * WSZ);
  bf16* kk = (bf16*)(ws + SZ + 4 * WSZ + SZ);
  bf16* vv = (bf16*)(ws + SZ + 4 * WSZ + 2 * SZ);
  bf16* om = xb;  // x_bf16 dead after gemm_qkv; reuse for attention output
  // total ws use: 4*SZ + 4*WSZ = 201,326,592 bytes (192 MiB)

  const int NTOT = TOK * DIM_;  // 24,117,248
  const int NW   = DIM_ * DIM_; // 1,048,576

  cvt_bf16<<<NTOT / 2048, 256, 0, stream>>>(x, xb, NTOT);
  cvt_bf16<<<NW / 2048, 256, 0, stream>>>(q_w, wq, NW);
  cvt_bf16<<<NW / 2048, 256, 0, stream>>>(k_w, wk, NW);
  cvt_bf16<<<NW / 2048, 256, 0, stream>>>(v_w, wv, NW);
  cvt_bf16<<<NW / 2048, 256, 0, stream>>>(o_w, wo, NW);

  dim3 gq(TOK / 128, DIM_ / 128, 3);  // 184 x 8 x 3
  gemm_qkv<<<gq, 256, 0, stream>>>(xb, wq, wk, wv, q_b, k_b, v_b, qq, kk, vv);

  norm_rope<<<dim3(SEQ, NFRM), 256, 0, stream>>>(qq, kk, nqw, nkw, fcos, fsin);

  attn_win<<<dim3(SEQ, NH_), 256, 0, stream>>>(qq, kk, vv, om);

  gemm_out<<<dim3(TOK / 128, DIM_ / 128), 256, 0, stream>>>(om, wo, o_b, out);
}